// Round 7
// baseline (254.361 us; speedup 1.0000x reference)
//
#include <hip/hip_runtime.h>
#include <stdint.h>

// FANeuron two-pass:
//  K1 (scan): sequential per-chain recurrence, compute-only. 64-thread block
//             = 128 chains (2 batch rows x 64 features); each lane runs TWO
//             independent chains interleaved -> fills the dependent-VALU
//             latency shadows a single chain leaves on a 1-wave/SIMD CU.
//             Depth-2-prefetch global_load_lds ring (DEPTH=4 slots), counted
//             s_waitcnt vmcnt(32) (next tile always in flight, never drained
//             to 0 mid-loop). Refractory as "next-ready step" nr.
//  K2 (emit): one thread per (chain, chunk) replays its chunk bit-exactly
//             from the seeded (ema, nr) state and writes va_trace + spikes.

#define L_CHUNK 256
#define TS 64          // timesteps per K1 tile
#define DEPTH 4        // LDS ring slots
#define K2_UNROLL 8

typedef const __attribute__((address_space(1))) uint32_t* gptr_t;
typedef __attribute__((address_space(3))) uint32_t* lptr_t;

__global__ __launch_bounds__(64, 1)
void fa_scan_kernel(const float* __restrict__ x,
                    const float* __restrict__ vb,
                    const float* __restrict__ A,
                    const float* __restrict__ th,
                    const float* __restrict__ gain,
                    const float* __restrict__ tref,
                    float* __restrict__ emas,   // [nchunks][N] (c>=1 used)
                    int*   __restrict__ nrs,    // [nchunks][N] (c>=1 used)
                    int B, int T, int F) {
#pragma clang fp contract(off)
    __shared__ float lds[DEPTH][2][TS][64];     // 128 KiB
    const int lane = threadIdx.x;
    const int gpb = F >> 6;                     // 64-feature groups per b
    const int halfB = B >> 1;
    const int bi = blockIdx.x;
    const int p = bi / gpb;                     // 0..halfB-1
    const int g = bi - p * gpb;
    const int f = (g << 6) + lane;
    const int b0 = p, b1 = p + halfB;
    const int i0 = b0 * F + f;
    const int i1 = b1 * F + f;
    const int N = B * F;

    // per-feature params (shared by both chains: they use the same f)
    const float vbf = vb[f], Af = A[f], thf = th[f], gf = gain[f];
    const float alpha = 0.001f;                 // f32(0.05/50)
    const int rs = (int)fmaxf(ceilf(tref[f] / 0.05f), 1.0f);

    // per-lane DMA source: lane l covers row (l>>4), 16B at col (l&15)*4
    const size_t lane_off = (size_t)(lane >> 4) * F + ((lane & 15) << 2);
    const float* g0 = x + (size_t)b0 * T * F + (size_t)(g << 6) + lane_off;
    const float* g1 = x + (size_t)b1 * T * F + (size_t)(g << 6) + lane_off;
    const int ntiles = T / TS;

    // issue tile J: 2 x 16 global_load_lds_dwordx4 into slot J&3.
    // LDS dest is wave-uniform; HW writes dest + lane*16 (linear layout
    // matches [4 rows][16 lanes x 16B] per instruction).
#define ISSUE_TILE(J)                                                         \
    do {                                                                      \
        const float* sa_ = g0 + (size_t)(J) * TS * F;                         \
        const float* sb_ = g1 + (size_t)(J) * TS * F;                         \
        float* da_ = &lds[(J) & (DEPTH - 1)][0][0][0];                        \
        float* db_ = &lds[(J) & (DEPTH - 1)][1][0][0];                        \
        _Pragma("unroll")                                                     \
        for (int jj = 0; jj < 16; ++jj)                                       \
            __builtin_amdgcn_global_load_lds(                                 \
                (gptr_t)(sa_ + (size_t)(4 * jj) * F),                         \
                (lptr_t)(da_ + 4 * jj * 64), 16, 0, 0);                       \
        _Pragma("unroll")                                                     \
        for (int jj = 0; jj < 16; ++jj)                                       \
            __builtin_amdgcn_global_load_lds(                                 \
                (gptr_t)(sb_ + (size_t)(4 * jj) * F),                         \
                (lptr_t)(db_ + 4 * jj * 64), 16, 0, 0);                       \
    } while (0)

    ISSUE_TILE(0);
    ISSUE_TILE(1);

    bool fastAll = __all((gf == 1.0f) && (Af == 1.0f) && (vbf == 0.0f));

    float ema0 = 0.0f, ema1 = 0.0f;
    int nr0 = 0, nr1 = 0;                       // relative to current tile

    for (int k = 0; k < ntiles; ++k) {
        // counted wait: tile k's 32 loads complete; tile k+1's 32 stay in flight
        if (k < ntiles - 1) asm volatile("s_waitcnt vmcnt(32)" ::: "memory");
        else                asm volatile("s_waitcnt vmcnt(0)"  ::: "memory");
        __builtin_amdgcn_sched_barrier(0);

        const int slot = k & (DEPTH - 1);

        if (k == 0) {
            // bit-exact t==0 seeding: ema = xt(0); first step then yields
            // fl(xt + alpha*0) = xt, so no special case in the loop.
            float xa = lds[0][0][0][lane];
            float xb = lds[0][1][0][lane];
            ema0 = fastAll ? xa : (xa * gf);
            ema1 = fastAll ? xb : (xb * gf);
        } else if ((k & 3) == 0) {              // L_CHUNK/TS == 4
            int c = k >> 2;
            emas[(size_t)c * N + i0] = ema0;
            nrs[(size_t)c * N + i0] = nr0 + k * TS;
            emas[(size_t)c * N + i1] = ema1;
            nrs[(size_t)c * N + i1] = nr1 + k * TS;
        }

        // ---- ping-pong batches of 8 per chain: LDS latency hides under
        //      the other batch's compute; two chains fill dep shadows.
        float ra0[8], rb0[8], ra1[8], rb1[8];
#pragma unroll
        for (int j = 0; j < 8; ++j) {
            ra0[j] = lds[slot][0][j][lane];
            ra1[j] = lds[slot][1][j][lane];
        }

        if (fastAll) {
#pragma unroll
            for (int t8 = 0; t8 < TS / 8; ++t8) {
                if (t8 < TS / 8 - 1) {
#pragma unroll
                    for (int j = 0; j < 8; ++j) {
                        rb0[j] = lds[slot][0][(t8 + 1) * 8 + j][lane];
                        rb1[j] = lds[slot][1][(t8 + 1) * 8 + j][lane];
                    }
                }
#pragma unroll
                for (int j = 0; j < 8; ++j) {
                    const int t = t8 * 8 + j;
                    {
                        float xv = ra0[j];
                        float d1 = xv - ema0;
                        float am = alpha * d1;
                        ema0 = ema0 + am;
                        float d2 = xv - ema0;
                        bool cross = fabsf(d2) >= thf;
                        bool tge = t >= nr0;
                        bool fired = cross && tge;
                        nr0 = fired ? (t + 1 + rs) : nr0;
                    }
                    {
                        float xv = ra1[j];
                        float d1 = xv - ema1;
                        float am = alpha * d1;
                        ema1 = ema1 + am;
                        float d2 = xv - ema1;
                        bool cross = fabsf(d2) >= thf;
                        bool tge = t >= nr1;
                        bool fired = cross && tge;
                        nr1 = fired ? (t + 1 + rs) : nr1;
                    }
                }
#pragma unroll
                for (int j = 0; j < 8; ++j) { ra0[j] = rb0[j]; ra1[j] = rb1[j]; }
            }
        } else {
#pragma unroll
            for (int t8 = 0; t8 < TS / 8; ++t8) {
                if (t8 < TS / 8 - 1) {
#pragma unroll
                    for (int j = 0; j < 8; ++j) {
                        rb0[j] = lds[slot][0][(t8 + 1) * 8 + j][lane];
                        rb1[j] = lds[slot][1][(t8 + 1) * 8 + j][lane];
                    }
                }
#pragma unroll
                for (int j = 0; j < 8; ++j) {
                    const int t = t8 * 8 + j;
                    {
                        float xt = ra0[j] * gf;
                        float d1 = xt - ema0;
                        float am = alpha * d1;
                        ema0 = ema0 + am;
                        float d2 = xt - ema0;
                        float av = Af * d2;
                        float vc = vbf - av;
                        float dv = vc - vbf;
                        bool cross = fabsf(dv) >= thf;
                        bool tge = t >= nr0;
                        bool fired = cross && tge;
                        nr0 = fired ? (t + 1 + rs) : nr0;
                    }
                    {
                        float xt = ra1[j] * gf;
                        float d1 = xt - ema1;
                        float am = alpha * d1;
                        ema1 = ema1 + am;
                        float d2 = xt - ema1;
                        float av = Af * d2;
                        float vc = vbf - av;
                        float dv = vc - vbf;
                        bool cross = fabsf(dv) >= thf;
                        bool tge = t >= nr1;
                        bool fired = cross && tge;
                        nr1 = fired ? (t + 1 + rs) : nr1;
                    }
                }
#pragma unroll
                for (int j = 0; j < 8; ++j) { ra0[j] = rb0[j]; ra1[j] = rb1[j]; }
            }
        }
        nr0 -= TS;                              // re-base to next tile
        nr1 -= TS;

        if (k + 2 < ntiles) ISSUE_TILE(k + 2);
    }
#undef ISSUE_TILE
}

__global__ __launch_bounds__(256)
void fa_emit_kernel(const float* __restrict__ x,
                    const float* __restrict__ vb,
                    const float* __restrict__ A,
                    const float* __restrict__ th,
                    const float* __restrict__ gain,
                    const float* __restrict__ tref,
                    const float* __restrict__ emas,
                    const int*   __restrict__ nrs,
                    float* __restrict__ out,
                    int B, int T, int F, int nchunks) {
#pragma clang fp contract(off)
    int N = B * F;
    int tid = blockIdx.x * blockDim.x + threadIdx.x;
    if (tid >= N * nchunks) return;
    int i = tid % N;
    int k = tid / N;
    int f = i % F;
    int b = i / F;
    const float vbf = vb[f], Af = A[f], thf = th[f], gf = gain[f];
    const float alpha = 0.001f;
    int rs = (int)fmaxf(ceilf(tref[f] / 0.05f), 1.0f);

    const float* xp = x + (size_t)b * T * F + f;
    float* va_out   = out + (size_t)b * (T + 1) * F + f;
    float* sp_out   = out + (size_t)B * (T + 1) * F + (size_t)b * (T + 1) * F + f;

    int tbeg = k * L_CHUNK;
    int tend = tbeg + L_CHUNK;
    if (tend > T) tend = T;

    float cur[K2_UNROLL], nxt[K2_UNROLL];
#pragma unroll
    for (int u = 0; u < K2_UNROLL; ++u) cur[u] = xp[(size_t)(tbeg + u) * F];

    float ema;
    int nr;
    if (k == 0) {
        ema = cur[0] * gf;     // t==0 seeding trick (see K1)
        nr = 0;
        va_out[0] = vbf;       // va_trace[:,0,:] = vb
    } else {
        ema = emas[(size_t)k * N + i];
        nr = nrs[(size_t)k * N + i];
    }

    float last_sp = 0.0f;
    for (int t0 = tbeg; t0 < tend; t0 += K2_UNROLL) {
        if (t0 + K2_UNROLL < tend) {
#pragma unroll
            for (int u = 0; u < K2_UNROLL; ++u)
                nxt[u] = xp[(size_t)(t0 + K2_UNROLL + u) * F];
        }
#pragma unroll
        for (int u = 0; u < K2_UNROLL; ++u) {
            int t = t0 + u;
            float xt = cur[u] * gf;
            float d1 = xt - ema;
            float am = alpha * d1;
            ema = ema + am;
            float d2 = xt - ema;
            float av = Af * d2;
            float vc = vbf - av;       // va_cand
            float dv = vc - vbf;
            bool cross = fabsf(dv) >= thf;
            bool tge = t >= nr;
            bool fired = cross && tge;
            float va_next = (cross || !tge) ? vbf : vc;
            nr = fired ? (t + 1 + rs) : nr;
            float spv = fired ? 1.0f : 0.0f;
            va_out[(size_t)(t + 1) * F] = va_next;
            sp_out[(size_t)t * F] = spv;
            last_sp = spv;
        }
#pragma unroll
        for (int u = 0; u < K2_UNROLL; ++u) cur[u] = nxt[u];
    }
    if (tend == T) sp_out[(size_t)T * F] = last_sp;   // spikes[:,T,:] = fired_{T-1}
}

// Fallback: monolithic (used only if ws too small / shape odd).
__global__ __launch_bounds__(64, 1)
void fa_neuron_mono(const float* __restrict__ x,
                    const float* __restrict__ vb,
                    const float* __restrict__ A,
                    const float* __restrict__ th,
                    const float* __restrict__ gain,
                    const float* __restrict__ tref,
                    float* __restrict__ out,
                    int B, int T, int F) {
#pragma clang fp contract(off)
    int tid = blockIdx.x * blockDim.x + threadIdx.x;
    if (tid >= B * F) return;
    int f = tid % F;
    int b = tid / F;
    const float vbf = vb[f], Af = A[f], thf = th[f], gf = gain[f];
    const float alpha = 0.001f;
    int rs = (int)fmaxf(ceilf(tref[f] / 0.05f), 1.0f);
    const float* xp = x + (size_t)b * T * F + f;
    float* va_out   = out + (size_t)b * (T + 1) * F + f;
    float* sp_out   = out + (size_t)B * (T + 1) * F + (size_t)b * (T + 1) * F + f;
    va_out[0] = vbf;
    float ema = 0.0f;
    int nr = 0;
    for (int t = 0; t < T; ++t) {
        float xt = xp[(size_t)t * F] * gf;
        if (t == 0) {
            ema = xt;
        } else {
            float d1 = xt - ema;
            float am = alpha * d1;
            ema = ema + am;
        }
        float d2 = xt - ema;
        float av = Af * d2;
        float vc = vbf - av;
        float dv = vc - vbf;
        bool cross = fabsf(dv) >= thf;
        bool tge = t >= nr;
        bool fired = cross && tge;
        float va_next = (cross || !tge) ? vbf : vc;
        nr = fired ? (t + 1 + rs) : nr;
        float spv = fired ? 1.0f : 0.0f;
        va_out[(size_t)(t + 1) * F] = va_next;
        sp_out[(size_t)t * F] = spv;
        if (t == T - 1) sp_out[(size_t)T * F] = spv;
    }
}

extern "C" void kernel_launch(void* const* d_in, const int* in_sizes, int n_in,
                              void* d_out, int out_size, void* d_ws, size_t ws_size,
                              hipStream_t stream) {
    const float* x    = (const float*)d_in[0];
    const float* vb   = (const float*)d_in[1];
    const float* A    = (const float*)d_in[2];
    const float* th   = (const float*)d_in[3];
    const float* gain = (const float*)d_in[4];
    const float* tref = (const float*)d_in[5];
    float* out = (float*)d_out;

    int F = in_sizes[1];                                   // 512
    long long BF = (long long)out_size / 2 - in_sizes[0];  // B*F
    int B = (int)(BF / F);                                 // 16
    int T = (int)(in_sizes[0] / BF);                       // 4096
    int N = B * F;

    int nchunks = (T + L_CHUNK - 1) / L_CHUNK;
    size_t ws_need = (size_t)nchunks * N * (sizeof(float) + sizeof(int));

    bool tiled_ok = (ws_size >= ws_need) && (T % L_CHUNK == 0) &&
                    (T % TS == 0) && (T / TS >= 4) && (F % 64 == 0) &&
                    (B % 2 == 0) && (L_CHUNK == 4 * TS);

    if (!tiled_ok) {
        int block = 64;
        int grid = (N + block - 1) / block;
        fa_neuron_mono<<<grid, block, 0, stream>>>(x, vb, A, th, gain, tref, out, B, T, F);
        return;
    }

    float* emas = (float*)d_ws;
    int*   nrs  = (int*)(emas + (size_t)nchunks * N);

    {
        int block = 64;
        int grid = (B / 2) * (F / 64);   // 2 chains per lane
        fa_scan_kernel<<<grid, block, 0, stream>>>(x, vb, A, th, gain, tref,
                                                   emas, nrs, B, T, F);
    }
    {
        int total = N * nchunks;
        int block = 256;
        int grid = (total + block - 1) / block;
        fa_emit_kernel<<<grid, block, 0, stream>>>(x, vb, A, th, gain, tref,
                                                   emas, nrs, out, B, T, F, nchunks);
    }
}